// Round 1
// baseline (226.085 us; speedup 1.0000x reference)
//
#include <hip/hip_runtime.h>

// Problem constants (from reference)
constexpr int kB   = 128;
constexpr int kU   = 4;
constexpr int kNBS = 64;
constexpr int kS   = 408;
constexpr int kS4  = kS / 4;                         // 102 float4 per row
constexpr unsigned kNQ = (unsigned)kB * kU * kNBS * kS4;   // 3,342,336 float4 groups
constexpr float kEmW     = 0.01f;
constexpr float kInvNRad = 1.0f / ((float)kB * kU * kNBS * kS);  // 1/13,369,344
constexpr float kInvNAtt = 1.0f / ((float)kB * kU * kS);         // 1/208,896

__global__ void __launch_bounds__(256)
prism_loss_kernel(const float4* __restrict__ atten_re,
                  const float4* __restrict__ atten_im,
                  const float4* __restrict__ rad_re,
                  const float4* __restrict__ rad_im,
                  const float4* __restrict__ tgt_re,
                  const float4* __restrict__ tgt_im,
                  const float4* __restrict__ weights,
                  float* __restrict__ out)
{
    float recv   = 0.0f;   // sum of se*weights
    float em_rad = 0.0f;   // sum of relu(|rad|-10)^2
    float em_att = 0.0f;   // sum of relu(|atten|-1)^2 (only counted once per atten elem)

    const unsigned tid    = blockIdx.x * blockDim.x + threadIdx.x;
    const unsigned stride = gridDim.x * blockDim.x;

    for (unsigned q = tid; q < kNQ; q += stride) {
        const unsigned r    = q / (unsigned)kS4;      // row in (B*U*NBS) — magic-mul
        const unsigned s4   = q - r * (unsigned)kS4;  // float4 index within row
        const unsigned arow = r >> 6;                 // r / NBS

        const float4 ar = atten_re[arow * kS4 + s4];
        const float4 ai = atten_im[arow * kS4 + s4];
        const float4 rr = rad_re[q];
        const float4 ri = rad_im[q];
        const float4 tr = tgt_re[q];
        const float4 ti = tgt_im[q];
        const float4 w  = weights[s4];

        const bool do_att = ((r & (kNBS - 1)) == 0); // count atten em term once per (b,u,s)

#define PRISM_LANE(c)                                                        \
        {                                                                    \
            const float a_r = ar.c, a_i = ai.c;                              \
            const float r_r = rr.c, r_i = ri.c;                              \
            const float pr = a_r * r_r - a_i * r_i;                          \
            const float pi = a_r * r_i + a_i * r_r;                          \
            const float dr = pr - tr.c;                                      \
            const float di = pi - ti.c;                                      \
            recv = fmaf((dr * dr + di * di), w.c, recv);                     \
            float rm = sqrtf(fmaf(r_r, r_r, r_i * r_i)) - 10.0f;             \
            rm = fmaxf(rm, 0.0f);                                            \
            em_rad = fmaf(rm, rm, em_rad);                                   \
            if (do_att) {                                                    \
                float am = sqrtf(fmaf(a_r, a_r, a_i * a_i)) - 1.0f;          \
                am = fmaxf(am, 0.0f);                                        \
                em_att = fmaf(am, am, em_att);                               \
            }                                                                \
        }
        PRISM_LANE(x)
        PRISM_LANE(y)
        PRISM_LANE(z)
        PRISM_LANE(w)
#undef PRISM_LANE
    }

    // Fold the three partials into one scalar per thread.
    float acc = recv + kEmW * (em_rad * kInvNRad + em_att * kInvNAtt);

    // Wave-64 butterfly reduction.
    #pragma unroll
    for (int off = 32; off > 0; off >>= 1)
        acc += __shfl_down(acc, off, 64);

    __shared__ float sdata[4];
    const int lane = threadIdx.x & 63;
    const int wave = threadIdx.x >> 6;
    if (lane == 0) sdata[wave] = acc;
    __syncthreads();
    if (threadIdx.x == 0) {
        const float t = sdata[0] + sdata[1] + sdata[2] + sdata[3];
        atomicAdd(out, t);
    }
}

extern "C" void kernel_launch(void* const* d_in, const int* in_sizes, int n_in,
                              void* d_out, int out_size, void* d_ws, size_t ws_size,
                              hipStream_t stream) {
    const float4* atten_re = (const float4*)d_in[0];
    const float4* atten_im = (const float4*)d_in[1];
    const float4* rad_re   = (const float4*)d_in[2];
    const float4* rad_im   = (const float4*)d_in[3];
    const float4* tgt_re   = (const float4*)d_in[4];
    const float4* tgt_im   = (const float4*)d_in[5];
    const float4* weights  = (const float4*)d_in[6];
    // d_in[7..10] (positions, ue_positions, view_directions, bs_antenna_ids)
    // are unused by the reference computation.
    float* out = (float*)d_out;

    // d_out is re-poisoned to 0xAA before every timed launch; zero it.
    hipMemsetAsync(out, 0, sizeof(float), stream);

    // 3264 blocks * 256 threads * 4 float4/thread == kNQ exactly.
    const int kBlocks = 3264;
    prism_loss_kernel<<<kBlocks, 256, 0, stream>>>(
        atten_re, atten_im, rad_re, rad_im, tgt_re, tgt_im, weights, out);
}

// Round 2
// 224.122 us; speedup vs baseline: 1.0088x; 1.0088x over previous
//
#include <hip/hip_runtime.h>

// Problem constants (from reference)
constexpr int kB   = 128;
constexpr int kU   = 4;
constexpr int kNBS = 64;
constexpr int kS   = 408;
constexpr int kS4  = kS / 4;                               // 102 float4 per row
constexpr unsigned kNQ = (unsigned)kB * kU * kNBS * kS4;   // 3,342,336 float4 groups
constexpr unsigned kThreads = kNQ / 4;                     // 835,584 = 8192 rows * 102
constexpr unsigned kRowStep = 8192;                        // rows advanced per i-step
constexpr float kEmW     = 0.01f;
constexpr float kInvNRad = 1.0f / ((float)kB * kU * kNBS * kS);
constexpr float kInvNAtt = 1.0f / ((float)kB * kU * kS);

// Mapping: tid in [0, 835584). row0 = tid/102, s4 = tid%102 (so q0 == tid).
// Thread handles rows row0 + 8192*i, i=0..3, all at the same s4.
//   streaming index: q_i = tid + i*835584          (no division!)
//   atten index:     abase + i*13056, abase = (row0>>6)*102 + s4
//   do_att: (row0 & 63) == 0 — covers each (arow, s) pair exactly once
//           since arow_i = (row0>>6) + 128*i sweeps all 512 atten rows.
__global__ void __launch_bounds__(256)
prism_loss_kernel(const float4* __restrict__ atten_re,
                  const float4* __restrict__ atten_im,
                  const float4* __restrict__ rad_re,
                  const float4* __restrict__ rad_im,
                  const float4* __restrict__ tgt_re,
                  const float4* __restrict__ tgt_im,
                  const float4* __restrict__ weights,
                  float* __restrict__ out)
{
    const unsigned tid  = blockIdx.x * 256 + threadIdx.x;   // grid sized exactly
    const unsigned row0 = tid / 102u;                       // one magic-mul div
    const unsigned s4   = tid - row0 * 102u;
    const unsigned abase = (row0 >> 6) * 102u + s4;
    const bool do_att = ((row0 & 63u) == 0u);

    const float4 w = weights[s4];

    // Issue ALL loads up front for maximum memory-level parallelism.
    float4 ar[4], ai[4], rr[4], ri[4], tr[4], ti[4];
    #pragma unroll
    for (int i = 0; i < 4; ++i) {
        const unsigned q = tid + (unsigned)i * kThreads;
        const unsigned a = abase + (unsigned)i * (kRowStep / kNBS) * 102u; // +i*13056
        ar[i] = atten_re[a];
        ai[i] = atten_im[a];
        rr[i] = rad_re[q];
        ri[i] = rad_im[q];
        tr[i] = tgt_re[q];
        ti[i] = tgt_im[q];
    }

    float recv   = 0.0f;
    float em_rad = 0.0f;
    float em_att = 0.0f;

    #pragma unroll
    for (int i = 0; i < 4; ++i) {
#define PRISM_LANE(c)                                                        \
        {                                                                    \
            const float a_r = ar[i].c, a_i = ai[i].c;                        \
            const float r_r = rr[i].c, r_i = ri[i].c;                        \
            const float pr = a_r * r_r - a_i * r_i;                          \
            const float pi = a_r * r_i + a_i * r_r;                          \
            const float dr = pr - tr[i].c;                                   \
            const float di = pi - ti[i].c;                                   \
            recv = fmaf((dr * dr + di * di), w.c, recv);                     \
            float rm = sqrtf(fmaf(r_r, r_r, r_i * r_i)) - 10.0f;             \
            rm = fmaxf(rm, 0.0f);                                            \
            em_rad = fmaf(rm, rm, em_rad);                                   \
            if (do_att) {                                                    \
                float am = sqrtf(fmaf(a_r, a_r, a_i * a_i)) - 1.0f;          \
                am = fmaxf(am, 0.0f);                                        \
                em_att = fmaf(am, am, em_att);                               \
            }                                                                \
        }
        PRISM_LANE(x)
        PRISM_LANE(y)
        PRISM_LANE(z)
        PRISM_LANE(w)
#undef PRISM_LANE
    }

    float acc = recv + kEmW * (em_rad * kInvNRad + em_att * kInvNAtt);

    // Wave-64 reduction.
    #pragma unroll
    for (int off = 32; off > 0; off >>= 1)
        acc += __shfl_down(acc, off, 64);

    __shared__ float sdata[4];
    const int lane = threadIdx.x & 63;
    const int wave = threadIdx.x >> 6;
    if (lane == 0) sdata[wave] = acc;
    __syncthreads();
    if (threadIdx.x == 0) {
        atomicAdd(out, sdata[0] + sdata[1] + sdata[2] + sdata[3]);
    }
}

extern "C" void kernel_launch(void* const* d_in, const int* in_sizes, int n_in,
                              void* d_out, int out_size, void* d_ws, size_t ws_size,
                              hipStream_t stream) {
    const float4* atten_re = (const float4*)d_in[0];
    const float4* atten_im = (const float4*)d_in[1];
    const float4* rad_re   = (const float4*)d_in[2];
    const float4* rad_im   = (const float4*)d_in[3];
    const float4* tgt_re   = (const float4*)d_in[4];
    const float4* tgt_im   = (const float4*)d_in[5];
    const float4* weights  = (const float4*)d_in[6];
    float* out = (float*)d_out;

    // d_out is re-poisoned to 0xAA before every timed launch; zero it.
    hipMemsetAsync(out, 0, sizeof(float), stream);

    // 3264 blocks * 256 threads == kThreads exactly (no bounds checks needed).
    prism_loss_kernel<<<(int)(kThreads / 256), 256, 0, stream>>>(
        atten_re, atten_im, rad_re, rad_im, tgt_re, tgt_im, weights, out);
}

// Round 4
// 223.698 us; speedup vs baseline: 1.0107x; 1.0019x over previous
//
#include <hip/hip_runtime.h>

// Problem constants (from reference)
constexpr int kB   = 128;
constexpr int kU   = 4;
constexpr int kNBS = 64;
constexpr int kS   = 408;
constexpr int kS4  = kS / 4;                               // 102 float4 per row
constexpr unsigned kNQ = (unsigned)kB * kU * kNBS * kS4;   // 3,342,336 float4 groups
constexpr unsigned kThreads = kNQ / 4;                     // 835,584 = 8192 rows * 102
constexpr unsigned kRowStep = 8192;                        // rows advanced per i-step
constexpr float kEmW     = 0.01f;
constexpr float kInvNRad = 1.0f / ((float)kB * kU * kNBS * kS);
constexpr float kInvNAtt = 1.0f / ((float)kB * kU * kS);

// Native clang vector type — __builtin_nontemporal_load requires this
// (HIP_vector_type<float,4> is a struct and is rejected).
typedef float vfloat4 __attribute__((ext_vector_type(4)));

// Mapping: tid in [0, 835584). row0 = tid/102, s4 = tid%102 (so q0 == tid).
// Thread handles rows row0 + 8192*i, i=0..3, all at the same s4.
//   streaming index: q_i = tid + i*835584          (no division!)
//   atten index:     abase + i*13056
//   do_att: (row0 & 63) == 0 — covers each (arow, s) pair exactly once.
//
// R4: rad_*/tgt_* (214 MB, read exactly once) via non-temporal loads (nt bit)
// to skip cache allocation on the zero-reuse streams. Atten/weights (64x
// reuse) stay on the cached path.
__global__ void __launch_bounds__(256)
prism_loss_kernel(const vfloat4* __restrict__ atten_re,
                  const vfloat4* __restrict__ atten_im,
                  const vfloat4* __restrict__ rad_re,
                  const vfloat4* __restrict__ rad_im,
                  const vfloat4* __restrict__ tgt_re,
                  const vfloat4* __restrict__ tgt_im,
                  const vfloat4* __restrict__ weights,
                  float* __restrict__ out)
{
    const unsigned tid  = blockIdx.x * 256 + threadIdx.x;   // grid sized exactly
    const unsigned row0 = tid / 102u;                       // one magic-mul div
    const unsigned s4   = tid - row0 * 102u;
    const unsigned abase = (row0 >> 6) * 102u + s4;
    const bool do_att = ((row0 & 63u) == 0u);

    const vfloat4 w = weights[s4];

    // Issue ALL loads up front; streaming arrays via non-temporal loads.
    vfloat4 ar[4], ai[4], rr[4], ri[4], tr[4], ti[4];
    #pragma unroll
    for (int i = 0; i < 4; ++i) {
        const unsigned q = tid + (unsigned)i * kThreads;
        const unsigned a = abase + (unsigned)i * (kRowStep / kNBS) * 102u; // +i*13056
        ar[i] = atten_re[a];
        ai[i] = atten_im[a];
        rr[i] = __builtin_nontemporal_load(&rad_re[q]);
        ri[i] = __builtin_nontemporal_load(&rad_im[q]);
        tr[i] = __builtin_nontemporal_load(&tgt_re[q]);
        ti[i] = __builtin_nontemporal_load(&tgt_im[q]);
    }

    float recv   = 0.0f;
    float em_rad = 0.0f;
    float em_att = 0.0f;

    #pragma unroll
    for (int i = 0; i < 4; ++i) {
        #pragma unroll
        for (int c = 0; c < 4; ++c) {
            const float a_r = ar[i][c], a_i = ai[i][c];
            const float r_r = rr[i][c], r_i = ri[i][c];
            const float pr = a_r * r_r - a_i * r_i;
            const float pi = a_r * r_i + a_i * r_r;
            const float dr = pr - tr[i][c];
            const float di = pi - ti[i][c];
            recv = fmaf((dr * dr + di * di), w[c], recv);
            float rm = sqrtf(fmaf(r_r, r_r, r_i * r_i)) - 10.0f;
            rm = fmaxf(rm, 0.0f);
            em_rad = fmaf(rm, rm, em_rad);
            if (do_att) {
                float am = sqrtf(fmaf(a_r, a_r, a_i * a_i)) - 1.0f;
                am = fmaxf(am, 0.0f);
                em_att = fmaf(am, am, em_att);
            }
        }
    }

    float acc = recv + kEmW * (em_rad * kInvNRad + em_att * kInvNAtt);

    // Wave-64 reduction.
    #pragma unroll
    for (int off = 32; off > 0; off >>= 1)
        acc += __shfl_down(acc, off, 64);

    __shared__ float sdata[4];
    const int lane = threadIdx.x & 63;
    const int wave = threadIdx.x >> 6;
    if (lane == 0) sdata[wave] = acc;
    __syncthreads();
    if (threadIdx.x == 0) {
        atomicAdd(out, sdata[0] + sdata[1] + sdata[2] + sdata[3]);
    }
}

extern "C" void kernel_launch(void* const* d_in, const int* in_sizes, int n_in,
                              void* d_out, int out_size, void* d_ws, size_t ws_size,
                              hipStream_t stream) {
    const vfloat4* atten_re = (const vfloat4*)d_in[0];
    const vfloat4* atten_im = (const vfloat4*)d_in[1];
    const vfloat4* rad_re   = (const vfloat4*)d_in[2];
    const vfloat4* rad_im   = (const vfloat4*)d_in[3];
    const vfloat4* tgt_re   = (const vfloat4*)d_in[4];
    const vfloat4* tgt_im   = (const vfloat4*)d_in[5];
    const vfloat4* weights  = (const vfloat4*)d_in[6];
    float* out = (float*)d_out;

    // d_out is re-poisoned to 0xAA before every timed launch; zero it.
    (void)hipMemsetAsync(out, 0, sizeof(float), stream);

    // 3264 blocks * 256 threads == kThreads exactly (no bounds checks needed).
    prism_loss_kernel<<<(int)(kThreads / 256), 256, 0, stream>>>(
        atten_re, atten_im, rad_re, rad_im, tgt_re, tgt_im, weights, out);
}

// Round 5
// 210.741 us; speedup vs baseline: 1.0728x; 1.0615x over previous
//
#include <hip/hip_runtime.h>

// Problem constants (from reference)
constexpr int kB   = 128;
constexpr int kU   = 4;
constexpr int kNBS = 64;
constexpr int kS   = 408;
constexpr int kS4  = kS / 4;                               // 102 float4 per row
constexpr unsigned kNQ = (unsigned)kB * kU * kNBS * kS4;   // 3,342,336 float4 groups
constexpr int kChunk   = 8;                                // NBS rows per thread
constexpr unsigned kThreads = kNQ / kChunk;                // 417,792 threads
constexpr float kEmW     = 0.01f;
constexpr float kInvNRad = 1.0f / ((float)kB * kU * kNBS * kS);
constexpr float kInvNAtt = 1.0f / ((float)kB * kU * kS);

// Native clang vector type — required by __builtin_nontemporal_load.
typedef float vfloat4 __attribute__((ext_vector_type(4)));

// R5 mapping: tid in [0, 417792).
//   s4    = tid % 102                  (fastest dim -> coalesced)
//   rem   = tid / 102   in [0, 4096)
//   chunk = rem % 8, bu = rem / 8      (bu in [0,512) = b*U+u)
//   rows r = bu*64 + chunk*8 + j, j=0..7; streaming q_j = r*102 + s4
//   atten index a = bu*102 + s4 — loaded ONCE, reused for all 8 rows.
// This cuts atten traffic 64x->8x per element (107 MB -> 13.4 MB on the
// vector-memory path). do_att only on chunk==0 (each (bu,s4) counted once).
__global__ void __launch_bounds__(256)
prism_loss_kernel(const vfloat4* __restrict__ atten_re,
                  const vfloat4* __restrict__ atten_im,
                  const vfloat4* __restrict__ rad_re,
                  const vfloat4* __restrict__ rad_im,
                  const vfloat4* __restrict__ tgt_re,
                  const vfloat4* __restrict__ tgt_im,
                  const vfloat4* __restrict__ weights,
                  float* __restrict__ out)
{
    const unsigned tid   = blockIdx.x * 256 + threadIdx.x;  // grid sized exactly
    const unsigned rem   = tid / 102u;                      // magic-mul div
    const unsigned s4    = tid - rem * 102u;
    const unsigned chunk = rem & 7u;
    const unsigned bu    = rem >> 3;
    const unsigned qbase = (bu * 64u + chunk * 8u) * 102u + s4;
    const unsigned abase = bu * 102u + s4;
    const bool do_att = (chunk == 0u);

    const vfloat4 w  = weights[s4];
    const vfloat4 ar = atten_re[abase];
    const vfloat4 ai = atten_im[abase];

    float recv   = 0.0f;
    float em_rad = 0.0f;
    float em_att = 0.0f;

    // Two batches of 4 rows: 16 NT loads in flight per batch (64 VGPRs data).
    #pragma unroll
    for (int half = 0; half < 2; ++half) {
        vfloat4 rr[4], ri[4], tr[4], ti[4];
        #pragma unroll
        for (int j = 0; j < 4; ++j) {
            const unsigned q = qbase + (unsigned)(half * 4 + j) * 102u;
            rr[j] = __builtin_nontemporal_load(&rad_re[q]);
            ri[j] = __builtin_nontemporal_load(&rad_im[q]);
            tr[j] = __builtin_nontemporal_load(&tgt_re[q]);
            ti[j] = __builtin_nontemporal_load(&tgt_im[q]);
        }
        #pragma unroll
        for (int j = 0; j < 4; ++j) {
            #pragma unroll
            for (int c = 0; c < 4; ++c) {
                const float a_r = ar[c], a_i = ai[c];
                const float r_r = rr[j][c], r_i = ri[j][c];
                const float pr = a_r * r_r - a_i * r_i;
                const float pi = a_r * r_i + a_i * r_r;
                const float dr = pr - tr[j][c];
                const float di = pi - ti[j][c];
                recv = fmaf((dr * dr + di * di), w[c], recv);
                float rm = sqrtf(fmaf(r_r, r_r, r_i * r_i)) - 10.0f;
                rm = fmaxf(rm, 0.0f);
                em_rad = fmaf(rm, rm, em_rad);
            }
        }
    }

    if (do_att) {
        #pragma unroll
        for (int c = 0; c < 4; ++c) {
            float am = sqrtf(fmaf(ar[c], ar[c], ai[c] * ai[c])) - 1.0f;
            am = fmaxf(am, 0.0f);
            em_att = fmaf(am, am, em_att);
        }
    }

    float acc = recv + kEmW * (em_rad * kInvNRad + em_att * kInvNAtt);

    // Wave-64 reduction.
    #pragma unroll
    for (int off = 32; off > 0; off >>= 1)
        acc += __shfl_down(acc, off, 64);

    __shared__ float sdata[4];
    const int lane = threadIdx.x & 63;
    const int wave = threadIdx.x >> 6;
    if (lane == 0) sdata[wave] = acc;
    __syncthreads();
    if (threadIdx.x == 0) {
        atomicAdd(out, sdata[0] + sdata[1] + sdata[2] + sdata[3]);
    }
}

extern "C" void kernel_launch(void* const* d_in, const int* in_sizes, int n_in,
                              void* d_out, int out_size, void* d_ws, size_t ws_size,
                              hipStream_t stream) {
    const vfloat4* atten_re = (const vfloat4*)d_in[0];
    const vfloat4* atten_im = (const vfloat4*)d_in[1];
    const vfloat4* rad_re   = (const vfloat4*)d_in[2];
    const vfloat4* rad_im   = (const vfloat4*)d_in[3];
    const vfloat4* tgt_re   = (const vfloat4*)d_in[4];
    const vfloat4* tgt_im   = (const vfloat4*)d_in[5];
    const vfloat4* weights  = (const vfloat4*)d_in[6];
    float* out = (float*)d_out;

    // d_out is re-poisoned to 0xAA before every timed launch; zero it.
    (void)hipMemsetAsync(out, 0, sizeof(float), stream);

    // 1632 blocks * 256 threads == kThreads exactly (no bounds checks needed).
    prism_loss_kernel<<<(int)(kThreads / 256), 256, 0, stream>>>(
        atten_re, atten_im, rad_re, rad_im, tgt_re, tgt_im, weights, out);
}